// Round 1
// baseline (6541.964 us; speedup 1.0000x reference)
//
#include <hip/hip_runtime.h>
#include <math.h>

// ---------------------------------------------------------------------------
// GCN 3-layer forward, fp32.
//  out = A_norm( relu(A_norm(relu(A_norm(x@W1)+b1... ) ) ) )  per reference:
//  per layer: Y = H @ W ;  out_i = dinv_i*( sum_{e: dst=i} dinv_src*Y_src
//                                           + dinv_i*Y_i ) / deg_i + b
//  deg includes self-loop, dinv = 1/sqrt(deg), cnt = deg.
// CSR-by-dst built on device each call (no float atomics in aggregation).
// ---------------------------------------------------------------------------

#define BLK 256

__global__ void init_deg_fill(int* __restrict__ deg, int* __restrict__ fill, int n) {
    int i = blockIdx.x * blockDim.x + threadIdx.x;
    if (i < n) { deg[i] = 1; fill[i] = 0; }   // deg starts at 1 (self-loop)
}

__global__ void count_deg(const int* __restrict__ dst, int* __restrict__ deg, int E) {
    int e = blockIdx.x * blockDim.x + threadIdx.x;
    if (e < E) atomicAdd(&deg[dst[e]], 1);
}

__global__ void compute_dinv(const int* __restrict__ deg, float* __restrict__ dinv, int n) {
    int i = blockIdx.x * blockDim.x + threadIdx.x;
    if (i < n) dinv[i] = 1.0f / sqrtf((float)deg[i]);
}

// ---- exclusive scan of (deg[i]-1) into rowptr, 3 passes ----
__global__ void scan_block_sums(const int* __restrict__ deg, int* __restrict__ bsum, int n) {
    __shared__ int s[BLK];
    int i = blockIdx.x * BLK + threadIdx.x;
    s[threadIdx.x] = (i < n) ? deg[i] - 1 : 0;
    __syncthreads();
    for (int off = BLK / 2; off > 0; off >>= 1) {
        if (threadIdx.x < off) s[threadIdx.x] += s[threadIdx.x + off];
        __syncthreads();
    }
    if (threadIdx.x == 0) bsum[blockIdx.x] = s[0];
}

__global__ void scan_partials_excl(int* __restrict__ bsum, int nb) {
    __shared__ int a[512];
    __shared__ int b[512];
    int t = threadIdx.x;
    int v = (t < nb) ? bsum[t] : 0;
    a[t] = v;
    __syncthreads();
    int* s = a; int* d = b;
    for (int off = 1; off < 512; off <<= 1) {
        int val = s[t];
        if (t >= off) val += s[t - off];
        d[t] = val;
        __syncthreads();
        int* tmp = s; s = d; d = tmp;
    }
    if (t < nb) bsum[t] = s[t] - v;   // exclusive
}

__global__ void scan_write_rowptr(const int* __restrict__ deg, const int* __restrict__ bsum,
                                  int* __restrict__ rowptr, int n) {
    __shared__ int a[BLK];
    __shared__ int b[BLK];
    int t = threadIdx.x;
    int i = blockIdx.x * BLK + t;
    int v = (i < n) ? deg[i] - 1 : 0;
    a[t] = v;
    __syncthreads();
    int* s = a; int* d = b;
    for (int off = 1; off < BLK; off <<= 1) {
        int val = s[t];
        if (t >= off) val += s[t - off];
        d[t] = val;
        __syncthreads();
        int* tmp = s; s = d; d = tmp;
    }
    if (i < n) rowptr[i] = (s[t] - v) + bsum[blockIdx.x];
}

__global__ void place_edges(const int* __restrict__ src, const int* __restrict__ dst,
                            const int* __restrict__ rowptr, int* __restrict__ fill,
                            int* __restrict__ colidx, int E) {
    int e = blockIdx.x * blockDim.x + threadIdx.x;
    if (e < E) {
        int d = dst[e];
        int pos = rowptr[d] + atomicAdd(&fill[d], 1);
        colidx[pos] = src[e];
    }
}

// ---- GEMM: Y[n,KOUT] = H[n,128] @ W[128,KOUT], W staged in LDS ----
template <int KOUT>
__global__ __launch_bounds__(256) void gemm_rows(const float* __restrict__ H,
                                                 const float* __restrict__ W,
                                                 float* __restrict__ Y, int n) {
    extern __shared__ float Wl[];            // 128*KOUT floats
    for (int idx = threadIdx.x; idx < 128 * KOUT; idx += 256) Wl[idx] = W[idx];
    __syncthreads();

    const int lane = threadIdx.x & 63;
    int wv = (blockIdx.x * 256 + threadIdx.x) >> 6;
    int nw = (gridDim.x * 256) >> 6;
    constexpr int RPW = 4;

    for (int row0 = wv * RPW; row0 < n; row0 += nw * RPW) {
        float2 h[RPW];
#pragma unroll
        for (int r = 0; r < RPW; r++) {
            int row = row0 + r;
            h[r] = (row < n) ? *(const float2*)(H + (size_t)row * 128 + lane * 2)
                             : make_float2(0.f, 0.f);
        }
        float acc[RPW][KOUT / 64];
#pragma unroll
        for (int r = 0; r < RPW; r++)
#pragma unroll
            for (int c = 0; c < KOUT / 64; c++) acc[r][c] = 0.f;

#pragma unroll
        for (int kk = 0; kk < 64; kk++) {
            float w0 = Wl[(2 * kk) * KOUT + lane];
            float w1 = Wl[(2 * kk + 1) * KOUT + lane];
            float w0b = 0.f, w1b = 0.f;
            if constexpr (KOUT == 128) {
                w0b = Wl[(2 * kk) * KOUT + 64 + lane];
                w1b = Wl[(2 * kk + 1) * KOUT + 64 + lane];
            }
#pragma unroll
            for (int r = 0; r < RPW; r++) {
                float a0 = __shfl(h[r].x, kk);
                float a1 = __shfl(h[r].y, kk);
                acc[r][0] += a0 * w0;
                acc[r][0] += a1 * w1;
                if constexpr (KOUT == 128) {
                    acc[r][1] += a0 * w0b;
                    acc[r][1] += a1 * w1b;
                }
            }
        }
#pragma unroll
        for (int r = 0; r < RPW; r++) {
            int row = row0 + r;
            if (row < n) {
                Y[(size_t)row * KOUT + lane] = acc[r][0];
                if constexpr (KOUT == 128) Y[(size_t)row * KOUT + 64 + lane] = acc[r][1];
            }
        }
    }
}

// ---- aggregation: wave per node, gather Y rows of in-neighbors ----
template <int KOUT, bool RELU>
__global__ __launch_bounds__(256) void agg_nodes(const float* __restrict__ Y,
                                                 const int* __restrict__ rowptr,
                                                 const int* __restrict__ deg,
                                                 const float* __restrict__ dinv,
                                                 const int* __restrict__ colidx,
                                                 const float* __restrict__ bias,
                                                 float* __restrict__ out, int n) {
    int wid = (blockIdx.x * blockDim.x + threadIdx.x) >> 6;
    int lane = threadIdx.x & 63;
    if (wid >= n) return;

    float di = dinv[wid];
    int start = rowptr[wid];
    int m = deg[wid] - 1;   // real incoming edges (excl. self-loop)

    if constexpr (KOUT == 128) {
        float2 ys = *(const float2*)(Y + (size_t)wid * 128 + lane * 2);
        float2 acc = make_float2(di * ys.x, di * ys.y);   // self: dinv_i * Y_i
        for (int base = 0; base < m; base += 64) {
            int e = base + lane;
            int s = 0; float w = 0.f;
            if (e < m) { s = colidx[start + e]; w = dinv[s]; }
            int lim = min(64, m - base);
            for (int j = 0; j < lim; j++) {
                int sj = __shfl(s, j);
                float wj = __shfl(w, j);
                float2 yv = *(const float2*)(Y + (size_t)sj * 128 + lane * 2);
                acc.x += wj * yv.x;
                acc.y += wj * yv.y;
            }
        }
        float scale = di / (float)deg[wid];
        float ox = acc.x * scale + bias[lane * 2];
        float oy = acc.y * scale + bias[lane * 2 + 1];
        if (RELU) { ox = fmaxf(ox, 0.f); oy = fmaxf(oy, 0.f); }
        *(float2*)(out + (size_t)wid * 128 + lane * 2) = make_float2(ox, oy);
    } else {
        float ys = Y[(size_t)wid * 64 + lane];
        float acc = di * ys;
        for (int base = 0; base < m; base += 64) {
            int e = base + lane;
            int s = 0; float w = 0.f;
            if (e < m) { s = colidx[start + e]; w = dinv[s]; }
            int lim = min(64, m - base);
            for (int j = 0; j < lim; j++) {
                int sj = __shfl(s, j);
                float wj = __shfl(w, j);
                acc += wj * Y[(size_t)sj * 64 + lane];
            }
        }
        float scale = di / (float)deg[wid];
        float o = acc * scale + bias[lane];
        if (RELU) o = fmaxf(o, 0.f);
        out[(size_t)wid * 64 + lane] = o;
    }
}

extern "C" void kernel_launch(void* const* d_in, const int* in_sizes, int n_in,
                              void* d_out, int out_size, void* d_ws, size_t ws_size,
                              hipStream_t stream) {
    const float* x  = (const float*)d_in[0];
    const int*   ei = (const int*)d_in[1];
    const float* W1 = (const float*)d_in[2];
    const float* b1 = (const float*)d_in[3];
    const float* W2 = (const float*)d_in[4];
    const float* b2 = (const float*)d_in[5];
    const float* W3 = (const float*)d_in[6];
    const float* b3 = (const float*)d_in[7];
    float* out = (float*)d_out;

    const int n = in_sizes[0] / 128;      // 100000
    const int E = in_sizes[1] / 2;        // 1600000
    const int* srcA = ei;
    const int* dstA = ei + E;

    // ---- workspace carve (aligned to 256B) ----
    auto alignup = [](size_t v) { return (v + 255) & ~(size_t)255; };
    char* base = (char*)d_ws;
    size_t off = 0;
    int* deg    = (int*)(base + off); off = alignup(off + (size_t)n * 4);
    int* fill   = (int*)(base + off); off = alignup(off + (size_t)n * 4);
    int* rowptr = (int*)(base + off); off = alignup(off + (size_t)n * 4);
    int* bsum   = (int*)(base + off); off = alignup(off + (size_t)1024 * 4);
    int* colidx = (int*)(base + off); off = alignup(off + (size_t)E * 4);
    float* dinv = (float*)(base + off); off = alignup(off + (size_t)n * 4);
    float* Hb   = (float*)(base + off); off = alignup(off + (size_t)n * 128 * 4);
    float* Yb   = (float*)(base + off); off = alignup(off + (size_t)n * 128 * 4);
    (void)ws_size;

    const int nbN = (n + BLK - 1) / BLK;      // 391
    const int nbE = (E + BLK - 1) / BLK;

    // ---- prep: degrees, dinv, CSR ----
    init_deg_fill<<<nbN, BLK, 0, stream>>>(deg, fill, n);
    count_deg<<<nbE, BLK, 0, stream>>>(dstA, deg, E);
    compute_dinv<<<nbN, BLK, 0, stream>>>(deg, dinv, n);
    scan_block_sums<<<nbN, BLK, 0, stream>>>(deg, bsum, n);
    scan_partials_excl<<<1, 512, 0, stream>>>(bsum, nbN);
    scan_write_rowptr<<<nbN, BLK, 0, stream>>>(deg, bsum, rowptr, n);
    place_edges<<<nbE, BLK, 0, stream>>>(srcA, dstA, rowptr, fill, colidx, E);

    const int aggBlocks = (n * 64 + BLK - 1) / BLK;   // wave per node

    // ---- layer 1: x @ W1 -> agg -> relu -> Hb ----
    gemm_rows<128><<<512, 256, 128 * 128 * 4, stream>>>(x, W1, Yb, n);
    agg_nodes<128, true><<<aggBlocks, BLK, 0, stream>>>(Yb, rowptr, deg, dinv, colidx, b1, Hb, n);

    // ---- layer 2 ----
    gemm_rows<128><<<512, 256, 128 * 128 * 4, stream>>>(Hb, W2, Yb, n);
    agg_nodes<128, true><<<aggBlocks, BLK, 0, stream>>>(Yb, rowptr, deg, dinv, colidx, b2, Hb, n);

    // ---- layer 3 (out dim 64, no relu) ----
    gemm_rows<64><<<512, 256, 128 * 64 * 4, stream>>>(Hb, W3, Yb, n);
    agg_nodes<64, false><<<aggBlocks, BLK, 0, stream>>>(Yb, rowptr, deg, dinv, colidx, b3, out, n);
}

// Round 2
// 660.442 us; speedup vs baseline: 9.9054x; 9.9054x over previous
//
#include <hip/hip_runtime.h>
#include <math.h>

// ---------------------------------------------------------------------------
// GCN 3-layer forward, fp32.
//  per layer: Y = H @ W ;  out_i = dinv_i*( sum_{e: dst=i} dinv_src*Y_src
//                                           + dinv_i*Y_i ) / deg_i + b
//  deg includes self-loop, dinv = 1/sqrt(deg), cnt = deg.
// CSR-by-dst built on device each call (no float atomics in aggregation).
// R2: replaced spilling shuffle-GEMM with LDS-tiled register-blocked GEMM
//     (acc[4][8] per lane, 32 VGPR accumulator -> no scratch traffic).
// ---------------------------------------------------------------------------

#define BLK 256

__global__ void init_deg_fill(int* __restrict__ deg, int* __restrict__ fill, int n) {
    int i = blockIdx.x * blockDim.x + threadIdx.x;
    if (i < n) { deg[i] = 1; fill[i] = 0; }   // deg starts at 1 (self-loop)
}

__global__ void count_deg(const int* __restrict__ dst, int* __restrict__ deg, int E) {
    int e = blockIdx.x * blockDim.x + threadIdx.x;
    if (e < E) atomicAdd(&deg[dst[e]], 1);
}

__global__ void compute_dinv(const int* __restrict__ deg, float* __restrict__ dinv, int n) {
    int i = blockIdx.x * blockDim.x + threadIdx.x;
    if (i < n) dinv[i] = 1.0f / sqrtf((float)deg[i]);
}

// ---- exclusive scan of (deg[i]-1) into rowptr, 3 passes ----
__global__ void scan_block_sums(const int* __restrict__ deg, int* __restrict__ bsum, int n) {
    __shared__ int s[BLK];
    int i = blockIdx.x * BLK + threadIdx.x;
    s[threadIdx.x] = (i < n) ? deg[i] - 1 : 0;
    __syncthreads();
    for (int off = BLK / 2; off > 0; off >>= 1) {
        if (threadIdx.x < off) s[threadIdx.x] += s[threadIdx.x + off];
        __syncthreads();
    }
    if (threadIdx.x == 0) bsum[blockIdx.x] = s[0];
}

__global__ void scan_partials_excl(int* __restrict__ bsum, int nb) {
    __shared__ int a[512];
    __shared__ int b[512];
    int t = threadIdx.x;
    int v = (t < nb) ? bsum[t] : 0;
    a[t] = v;
    __syncthreads();
    int* s = a; int* d = b;
    for (int off = 1; off < 512; off <<= 1) {
        int val = s[t];
        if (t >= off) val += s[t - off];
        d[t] = val;
        __syncthreads();
        int* tmp = s; s = d; d = tmp;
    }
    if (t < nb) bsum[t] = s[t] - v;   // exclusive
}

__global__ void scan_write_rowptr(const int* __restrict__ deg, const int* __restrict__ bsum,
                                  int* __restrict__ rowptr, int n) {
    __shared__ int a[BLK];
    __shared__ int b[BLK];
    int t = threadIdx.x;
    int i = blockIdx.x * BLK + t;
    int v = (i < n) ? deg[i] - 1 : 0;
    a[t] = v;
    __syncthreads();
    int* s = a; int* d = b;
    for (int off = 1; off < BLK; off <<= 1) {
        int val = s[t];
        if (t >= off) val += s[t - off];
        d[t] = val;
        __syncthreads();
        int* tmp = s; s = d; d = tmp;
    }
    if (i < n) rowptr[i] = (s[t] - v) + bsum[blockIdx.x];
}

__global__ void place_edges(const int* __restrict__ src, const int* __restrict__ dst,
                            const int* __restrict__ rowptr, int* __restrict__ fill,
                            int* __restrict__ colidx, int E) {
    int e = blockIdx.x * blockDim.x + threadIdx.x;
    if (e < E) {
        int d = dst[e];
        int pos = rowptr[d] + atomicAdd(&fill[d], 1);
        colidx[pos] = src[e];
    }
}

// ---- GEMM: Y[n,KOUT] = H[n,128] @ W[128,KOUT] ----
// Block 256 thr = 4 waves. Tile: (KOUT==128 ? 64 : 128) rows x KOUT cols.
// Per lane: 4 rows x 8 contiguous cols -> acc[4][8] (32 VGPR). k-tiles of 32.
template <int KOUT>
__global__ __launch_bounds__(256) void gemm_tiled(const float* __restrict__ H,
                                                  const float* __restrict__ W,
                                                  float* __restrict__ Y, int n) {
    constexpr int ROWS = (KOUT == 128) ? 64 : 128;
    constexpr int HSTR = 36;  // padded k-stride: float4 aligned, conflict-free reads
    __shared__ float Hl[ROWS][HSTR];   // [row][kk]
    __shared__ float Wl[32][KOUT];     // [kk][c]

    const int t = threadIdx.x;
    const int wave = t >> 6, lane = t & 63;
    const int rg = lane >> 3;          // 0..7 row group
    const int cg = lane & 7;           // 0..7 col group
    const int rpanel = (KOUT == 128) ? (wave >> 1) : wave;
    const int cpanel = (KOUT == 128) ? (wave & 1) : 0;
    const int row0 = blockIdx.x * ROWS;
    const int cbase = cpanel * 64 + cg * 8;

    float acc[4][8];
#pragma unroll
    for (int i = 0; i < 4; i++)
#pragma unroll
        for (int j = 0; j < 8; j++) acc[i][j] = 0.f;

    for (int kt = 0; kt < 128; kt += 32) {
        // stage H tile: ROWS x 32 (8 threads/row, float4 each; coalesced 128B/row)
#pragma unroll
        for (int s = 0; s < ROWS / 32; s++) {
            int r = s * 32 + (t >> 3);
            int kk = (t & 7) * 4;
            int row = row0 + r;
            float4 v = make_float4(0.f, 0.f, 0.f, 0.f);
            if (row < n) v = *(const float4*)(H + (size_t)row * 128 + kt + kk);
            Hl[r][kk] = v.x; Hl[r][kk + 1] = v.y; Hl[r][kk + 2] = v.z; Hl[r][kk + 3] = v.w;
        }
        // stage W tile: 32 x KOUT, contiguous chunk
        {
            const float* Wg = W + (size_t)kt * KOUT;
            float* Wf = &Wl[0][0];
            for (int idx = t * 4; idx < 32 * KOUT; idx += 1024) {
                *(float4*)(Wf + idx) = *(const float4*)(Wg + idx);
            }
        }
        __syncthreads();

#pragma unroll 2
        for (int kk = 0; kk < 32; kk += 4) {
            float4 a[4];
#pragma unroll
            for (int i = 0; i < 4; i++)
                a[i] = *(const float4*)(&Hl[rpanel * 32 + rg + 8 * i][kk]);
#pragma unroll
            for (int q = 0; q < 4; q++) {
                float4 w0 = *(const float4*)(&Wl[kk + q][cbase]);
                float4 w1 = *(const float4*)(&Wl[kk + q][cbase + 4]);
#pragma unroll
                for (int i = 0; i < 4; i++) {
                    float av = (q == 0) ? a[i].x : (q == 1) ? a[i].y : (q == 2) ? a[i].z : a[i].w;
                    acc[i][0] += av * w0.x; acc[i][1] += av * w0.y;
                    acc[i][2] += av * w0.z; acc[i][3] += av * w0.w;
                    acc[i][4] += av * w1.x; acc[i][5] += av * w1.y;
                    acc[i][6] += av * w1.z; acc[i][7] += av * w1.w;
                }
            }
        }
        __syncthreads();
    }

#pragma unroll
    for (int i = 0; i < 4; i++) {
        int row = row0 + rpanel * 32 + rg + 8 * i;
        if (row < n) {
            float* yp = Y + (size_t)row * KOUT + cbase;
            *(float4*)yp = make_float4(acc[i][0], acc[i][1], acc[i][2], acc[i][3]);
            *(float4*)(yp + 4) = make_float4(acc[i][4], acc[i][5], acc[i][6], acc[i][7]);
        }
    }
}

// ---- aggregation: wave per node, gather Y rows of in-neighbors ----
template <int KOUT, bool RELU>
__global__ __launch_bounds__(256) void agg_nodes(const float* __restrict__ Y,
                                                 const int* __restrict__ rowptr,
                                                 const int* __restrict__ deg,
                                                 const float* __restrict__ dinv,
                                                 const int* __restrict__ colidx,
                                                 const float* __restrict__ bias,
                                                 float* __restrict__ out, int n) {
    int wid = (blockIdx.x * blockDim.x + threadIdx.x) >> 6;
    int lane = threadIdx.x & 63;
    if (wid >= n) return;

    float di = dinv[wid];
    int start = rowptr[wid];
    int m = deg[wid] - 1;   // real incoming edges (excl. self-loop)

    if constexpr (KOUT == 128) {
        float2 ys = *(const float2*)(Y + (size_t)wid * 128 + lane * 2);
        float2 acc = make_float2(di * ys.x, di * ys.y);   // self: dinv_i * Y_i
        for (int base = 0; base < m; base += 64) {
            int e = base + lane;
            int s = 0; float w = 0.f;
            if (e < m) { s = colidx[start + e]; w = dinv[s]; }
            int lim = min(64, m - base);
            for (int j = 0; j < lim; j++) {
                int sj = __shfl(s, j);
                float wj = __shfl(w, j);
                float2 yv = *(const float2*)(Y + (size_t)sj * 128 + lane * 2);
                acc.x += wj * yv.x;
                acc.y += wj * yv.y;
            }
        }
        float scale = di / (float)deg[wid];
        float ox = acc.x * scale + bias[lane * 2];
        float oy = acc.y * scale + bias[lane * 2 + 1];
        if (RELU) { ox = fmaxf(ox, 0.f); oy = fmaxf(oy, 0.f); }
        *(float2*)(out + (size_t)wid * 128 + lane * 2) = make_float2(ox, oy);
    } else {
        float ys = Y[(size_t)wid * 64 + lane];
        float acc = di * ys;
        for (int base = 0; base < m; base += 64) {
            int e = base + lane;
            int s = 0; float w = 0.f;
            if (e < m) { s = colidx[start + e]; w = dinv[s]; }
            int lim = min(64, m - base);
            for (int j = 0; j < lim; j++) {
                int sj = __shfl(s, j);
                float wj = __shfl(w, j);
                acc += wj * Y[(size_t)sj * 64 + lane];
            }
        }
        float scale = di / (float)deg[wid];
        float o = acc * scale + bias[lane];
        if (RELU) o = fmaxf(o, 0.f);
        out[(size_t)wid * 64 + lane] = o;
    }
}

extern "C" void kernel_launch(void* const* d_in, const int* in_sizes, int n_in,
                              void* d_out, int out_size, void* d_ws, size_t ws_size,
                              hipStream_t stream) {
    const float* x  = (const float*)d_in[0];
    const int*   ei = (const int*)d_in[1];
    const float* W1 = (const float*)d_in[2];
    const float* b1 = (const float*)d_in[3];
    const float* W2 = (const float*)d_in[4];
    const float* b2 = (const float*)d_in[5];
    const float* W3 = (const float*)d_in[6];
    const float* b3 = (const float*)d_in[7];
    float* out = (float*)d_out;

    const int n = in_sizes[0] / 128;      // 100000
    const int E = in_sizes[1] / 2;        // 1600000
    const int* srcA = ei;
    const int* dstA = ei + E;

    // ---- workspace carve (aligned to 256B) ----
    auto alignup = [](size_t v) { return (v + 255) & ~(size_t)255; };
    char* base = (char*)d_ws;
    size_t off = 0;
    int* deg    = (int*)(base + off); off = alignup(off + (size_t)n * 4);
    int* fill   = (int*)(base + off); off = alignup(off + (size_t)n * 4);
    int* rowptr = (int*)(base + off); off = alignup(off + (size_t)n * 4);
    int* bsum   = (int*)(base + off); off = alignup(off + (size_t)1024 * 4);
    int* colidx = (int*)(base + off); off = alignup(off + (size_t)E * 4);
    float* dinv = (float*)(base + off); off = alignup(off + (size_t)n * 4);
    float* Hb   = (float*)(base + off); off = alignup(off + (size_t)n * 128 * 4);
    float* Yb   = (float*)(base + off); off = alignup(off + (size_t)n * 128 * 4);
    (void)ws_size;

    const int nbN = (n + BLK - 1) / BLK;      // 391
    const int nbE = (E + BLK - 1) / BLK;

    // ---- prep: degrees, dinv, CSR ----
    init_deg_fill<<<nbN, BLK, 0, stream>>>(deg, fill, n);
    count_deg<<<nbE, BLK, 0, stream>>>(dstA, deg, E);
    compute_dinv<<<nbN, BLK, 0, stream>>>(deg, dinv, n);
    scan_block_sums<<<nbN, BLK, 0, stream>>>(deg, bsum, n);
    scan_partials_excl<<<1, 512, 0, stream>>>(bsum, nbN);
    scan_write_rowptr<<<nbN, BLK, 0, stream>>>(deg, bsum, rowptr, n);
    place_edges<<<nbE, BLK, 0, stream>>>(srcA, dstA, rowptr, fill, colidx, E);

    const int aggBlocks = (n * 64 + BLK - 1) / BLK;   // wave per node

    // ---- layer 1: x @ W1 -> agg -> relu -> Hb ----
    gemm_tiled<128><<<(n + 63) / 64, 256, 0, stream>>>(x, W1, Yb, n);
    agg_nodes<128, true><<<aggBlocks, BLK, 0, stream>>>(Yb, rowptr, deg, dinv, colidx, b1, Hb, n);

    // ---- layer 2 ----
    gemm_tiled<128><<<(n + 63) / 64, 256, 0, stream>>>(Hb, W2, Yb, n);
    agg_nodes<128, true><<<aggBlocks, BLK, 0, stream>>>(Yb, rowptr, deg, dinv, colidx, b2, Hb, n);

    // ---- layer 3 (out dim 64, no relu) ----
    gemm_tiled<64><<<(n + 127) / 128, 256, 0, stream>>>(Hb, W3, Yb, n);
    agg_nodes<64, false><<<aggBlocks, BLK, 0, stream>>>(Yb, rowptr, deg, dinv, colidx, b3, out, n);
}

// Round 3
// 612.457 us; speedup vs baseline: 10.6815x; 1.0783x over previous
//
#include <hip/hip_runtime.h>
#include <math.h>

// ---------------------------------------------------------------------------
// GCN 3-layer forward, fp32.
//  per layer: Y = H @ W ;  out_i = dinv_i*( sum_{e: dst=i} dinv_src*Y_src
//                                           + dinv_i*Y_i ) / deg_i + b
// CSR-by-dst built on device each call (no float atomics in aggregation).
// R2: LDS-tiled register-blocked GEMM (no spills).
// R3: latency-optimized aggregation — multiple edge-rows in flight per wave
//     (lane-halves/quarters own whole rows; explicit 4x unroll).
// ---------------------------------------------------------------------------

#define BLK 256

__global__ void init_deg_fill(int* __restrict__ deg, int* __restrict__ fill, int n) {
    int i = blockIdx.x * blockDim.x + threadIdx.x;
    if (i < n) { deg[i] = 1; fill[i] = 0; }   // deg starts at 1 (self-loop)
}

__global__ void count_deg(const int* __restrict__ dst, int* __restrict__ deg, int E) {
    int e = blockIdx.x * blockDim.x + threadIdx.x;
    if (e < E) atomicAdd(&deg[dst[e]], 1);
}

__global__ void compute_dinv(const int* __restrict__ deg, float* __restrict__ dinv, int n) {
    int i = blockIdx.x * blockDim.x + threadIdx.x;
    if (i < n) dinv[i] = 1.0f / sqrtf((float)deg[i]);
}

// ---- exclusive scan of (deg[i]-1) into rowptr, 3 passes ----
__global__ void scan_block_sums(const int* __restrict__ deg, int* __restrict__ bsum, int n) {
    __shared__ int s[BLK];
    int i = blockIdx.x * BLK + threadIdx.x;
    s[threadIdx.x] = (i < n) ? deg[i] - 1 : 0;
    __syncthreads();
    for (int off = BLK / 2; off > 0; off >>= 1) {
        if (threadIdx.x < off) s[threadIdx.x] += s[threadIdx.x + off];
        __syncthreads();
    }
    if (threadIdx.x == 0) bsum[blockIdx.x] = s[0];
}

__global__ void scan_partials_excl(int* __restrict__ bsum, int nb) {
    __shared__ int a[512];
    __shared__ int b[512];
    int t = threadIdx.x;
    int v = (t < nb) ? bsum[t] : 0;
    a[t] = v;
    __syncthreads();
    int* s = a; int* d = b;
    for (int off = 1; off < 512; off <<= 1) {
        int val = s[t];
        if (t >= off) val += s[t - off];
        d[t] = val;
        __syncthreads();
        int* tmp = s; s = d; d = tmp;
    }
    if (t < nb) bsum[t] = s[t] - v;   // exclusive
}

__global__ void scan_write_rowptr(const int* __restrict__ deg, const int* __restrict__ bsum,
                                  int* __restrict__ rowptr, int n) {
    __shared__ int a[BLK];
    __shared__ int b[BLK];
    int t = threadIdx.x;
    int i = blockIdx.x * BLK + t;
    int v = (i < n) ? deg[i] - 1 : 0;
    a[t] = v;
    __syncthreads();
    int* s = a; int* d = b;
    for (int off = 1; off < BLK; off <<= 1) {
        int val = s[t];
        if (t >= off) val += s[t - off];
        d[t] = val;
        __syncthreads();
        int* tmp = s; s = d; d = tmp;
    }
    if (i < n) rowptr[i] = (s[t] - v) + bsum[blockIdx.x];
}

__global__ void place_edges(const int* __restrict__ src, const int* __restrict__ dst,
                            const int* __restrict__ rowptr, int* __restrict__ fill,
                            int* __restrict__ colidx, int E) {
    int e = blockIdx.x * blockDim.x + threadIdx.x;
    if (e < E) {
        int d = dst[e];
        int pos = rowptr[d] + atomicAdd(&fill[d], 1);
        colidx[pos] = src[e];
    }
}

// ---- GEMM: Y[n,KOUT] = H[n,128] @ W[128,KOUT] ----
// Block 256 thr = 4 waves. Tile: (KOUT==128 ? 64 : 128) rows x KOUT cols.
// Per lane: 4 rows x 8 contiguous cols -> acc[4][8] (32 VGPR). k-tiles of 32.
template <int KOUT>
__global__ __launch_bounds__(256) void gemm_tiled(const float* __restrict__ H,
                                                  const float* __restrict__ W,
                                                  float* __restrict__ Y, int n) {
    constexpr int ROWS = (KOUT == 128) ? 64 : 128;
    constexpr int HSTR = 36;  // padded k-stride: float4 aligned, conflict-free reads
    __shared__ float Hl[ROWS][HSTR];   // [row][kk]
    __shared__ float Wl[32][KOUT];     // [kk][c]

    const int t = threadIdx.x;
    const int wave = t >> 6, lane = t & 63;
    const int rg = lane >> 3;          // 0..7 row group
    const int cg = lane & 7;           // 0..7 col group
    const int rpanel = (KOUT == 128) ? (wave >> 1) : wave;
    const int cpanel = (KOUT == 128) ? (wave & 1) : 0;
    const int row0 = blockIdx.x * ROWS;
    const int cbase = cpanel * 64 + cg * 8;

    float acc[4][8];
#pragma unroll
    for (int i = 0; i < 4; i++)
#pragma unroll
        for (int j = 0; j < 8; j++) acc[i][j] = 0.f;

    for (int kt = 0; kt < 128; kt += 32) {
        // stage H tile: ROWS x 32 (8 threads/row, float4 each; coalesced 128B/row)
#pragma unroll
        for (int s = 0; s < ROWS / 32; s++) {
            int r = s * 32 + (t >> 3);
            int kk = (t & 7) * 4;
            int row = row0 + r;
            float4 v = make_float4(0.f, 0.f, 0.f, 0.f);
            if (row < n) v = *(const float4*)(H + (size_t)row * 128 + kt + kk);
            Hl[r][kk] = v.x; Hl[r][kk + 1] = v.y; Hl[r][kk + 2] = v.z; Hl[r][kk + 3] = v.w;
        }
        // stage W tile: 32 x KOUT, contiguous chunk
        {
            const float* Wg = W + (size_t)kt * KOUT;
            float* Wf = &Wl[0][0];
            for (int idx = t * 4; idx < 32 * KOUT; idx += 1024) {
                *(float4*)(Wf + idx) = *(const float4*)(Wg + idx);
            }
        }
        __syncthreads();

#pragma unroll 2
        for (int kk = 0; kk < 32; kk += 4) {
            float4 a[4];
#pragma unroll
            for (int i = 0; i < 4; i++)
                a[i] = *(const float4*)(&Hl[rpanel * 32 + rg + 8 * i][kk]);
#pragma unroll
            for (int q = 0; q < 4; q++) {
                float4 w0 = *(const float4*)(&Wl[kk + q][cbase]);
                float4 w1 = *(const float4*)(&Wl[kk + q][cbase + 4]);
#pragma unroll
                for (int i = 0; i < 4; i++) {
                    float av = (q == 0) ? a[i].x : (q == 1) ? a[i].y : (q == 2) ? a[i].z : a[i].w;
                    acc[i][0] += av * w0.x; acc[i][1] += av * w0.y;
                    acc[i][2] += av * w0.z; acc[i][3] += av * w0.w;
                    acc[i][4] += av * w1.x; acc[i][5] += av * w1.y;
                    acc[i][6] += av * w1.z; acc[i][7] += av * w1.w;
                }
            }
        }
        __syncthreads();
    }

#pragma unroll
    for (int i = 0; i < 4; i++) {
        int row = row0 + rpanel * 32 + rg + 8 * i;
        if (row < n) {
            float* yp = Y + (size_t)row * KOUT + cbase;
            *(float4*)yp = make_float4(acc[i][0], acc[i][1], acc[i][2], acc[i][3]);
            *(float4*)(yp + 4) = make_float4(acc[i][4], acc[i][5], acc[i][6], acc[i][7]);
        }
    }
}

// ---- aggregation, KOUT=128: wave per node; each lane-half owns a full row
// (float4 per lane over 32 lanes = 128 cols). 2 edges per load instruction,
// 4x unrolled -> 8 independent row-loads in flight per wave. ----
template <bool RELU>
__global__ __launch_bounds__(256) void agg128(const float* __restrict__ Y,
                                              const int* __restrict__ rowptr,
                                              const int* __restrict__ deg,
                                              const float* __restrict__ dinv,
                                              const int* __restrict__ colidx,
                                              const float* __restrict__ bias,
                                              float* __restrict__ out, int n) {
    int wid = (blockIdx.x * blockDim.x + threadIdx.x) >> 6;
    int lane = threadIdx.x & 63;
    if (wid >= n) return;
    const int half = lane >> 5;      // which edge of a pair
    const int l5 = lane & 31;        // col group: cols l5*4 .. l5*4+3

    float di = dinv[wid];
    int start = rowptr[wid];
    int dg = deg[wid];
    int m = dg - 1;                  // real incoming edges (excl. self-loop)

    float4 acc = make_float4(0.f, 0.f, 0.f, 0.f);
    if (half == 0) {                 // self term: dinv_i * Y_i
        float4 ys = *(const float4*)(Y + (size_t)wid * 128 + l5 * 4);
        acc.x = di * ys.x; acc.y = di * ys.y; acc.z = di * ys.z; acc.w = di * ys.w;
    }

    for (int base = 0; base < m; base += 64) {
        int e = base + lane;
        int s = 0; float w = 0.f;
        if (e < m) { s = colidx[start + e]; w = dinv[s]; }
        int lim = min(64, m - base);
        int limr = (lim + 7) & ~7;   // multiple of 8; shfl idx stays <= 63
        for (int j = 0; j < limr; j += 8) {
#pragma unroll
            for (int k = 0; k < 4; k++) {
                int eL = j + 2 * k + half;          // this half's edge slot
                int sE = __shfl(s, eL);             // w=0,s=0 for slots >= lim
                float wE = __shfl(w, eL);
                float4 yv = *(const float4*)(Y + (size_t)sE * 128 + l5 * 4);
                acc.x += wE * yv.x; acc.y += wE * yv.y;
                acc.z += wE * yv.z; acc.w += wE * yv.w;
            }
        }
    }
    // combine the two halves
    acc.x += __shfl_xor(acc.x, 32);
    acc.y += __shfl_xor(acc.y, 32);
    acc.z += __shfl_xor(acc.z, 32);
    acc.w += __shfl_xor(acc.w, 32);

    if (half == 0) {
        float scale = di / (float)dg;
        float4 bv = *(const float4*)(bias + l5 * 4);
        float4 o;
        o.x = acc.x * scale + bv.x;
        o.y = acc.y * scale + bv.y;
        o.z = acc.z * scale + bv.z;
        o.w = acc.w * scale + bv.w;
        if (RELU) {
            o.x = fmaxf(o.x, 0.f); o.y = fmaxf(o.y, 0.f);
            o.z = fmaxf(o.z, 0.f); o.w = fmaxf(o.w, 0.f);
        }
        *(float4*)(out + (size_t)wid * 128 + l5 * 4) = o;
    }
}

// ---- aggregation, KOUT=64: lane-quarters own a row (16 lanes x float4),
// 4 edges per load instruction, 4x unrolled -> 16 rows in flight. ----
template <bool RELU>
__global__ __launch_bounds__(256) void agg64(const float* __restrict__ Y,
                                             const int* __restrict__ rowptr,
                                             const int* __restrict__ deg,
                                             const float* __restrict__ dinv,
                                             const int* __restrict__ colidx,
                                             const float* __restrict__ bias,
                                             float* __restrict__ out, int n) {
    int wid = (blockIdx.x * blockDim.x + threadIdx.x) >> 6;
    int lane = threadIdx.x & 63;
    if (wid >= n) return;
    const int q = lane >> 4;         // which edge of a quad
    const int l4 = lane & 15;        // col group: cols l4*4 .. l4*4+3

    float di = dinv[wid];
    int start = rowptr[wid];
    int dg = deg[wid];
    int m = dg - 1;

    float4 acc = make_float4(0.f, 0.f, 0.f, 0.f);
    if (q == 0) {
        float4 ys = *(const float4*)(Y + (size_t)wid * 64 + l4 * 4);
        acc.x = di * ys.x; acc.y = di * ys.y; acc.z = di * ys.z; acc.w = di * ys.w;
    }

    for (int base = 0; base < m; base += 64) {
        int e = base + lane;
        int s = 0; float w = 0.f;
        if (e < m) { s = colidx[start + e]; w = dinv[s]; }
        int lim = min(64, m - base);
        int limr = (lim + 15) & ~15;  // multiple of 16; shfl idx <= 63
        for (int j = 0; j < limr; j += 16) {
#pragma unroll
            for (int k = 0; k < 4; k++) {
                int eL = j + 4 * k + q;
                int sE = __shfl(s, eL);
                float wE = __shfl(w, eL);
                float4 yv = *(const float4*)(Y + (size_t)sE * 64 + l4 * 4);
                acc.x += wE * yv.x; acc.y += wE * yv.y;
                acc.z += wE * yv.z; acc.w += wE * yv.w;
            }
        }
    }
    // combine the four quarters
    acc.x += __shfl_xor(acc.x, 16); acc.x += __shfl_xor(acc.x, 32);
    acc.y += __shfl_xor(acc.y, 16); acc.y += __shfl_xor(acc.y, 32);
    acc.z += __shfl_xor(acc.z, 16); acc.z += __shfl_xor(acc.z, 32);
    acc.w += __shfl_xor(acc.w, 16); acc.w += __shfl_xor(acc.w, 32);

    if (q == 0) {
        float scale = di / (float)dg;
        float4 bv = *(const float4*)(bias + l4 * 4);
        float4 o;
        o.x = acc.x * scale + bv.x;
        o.y = acc.y * scale + bv.y;
        o.z = acc.z * scale + bv.z;
        o.w = acc.w * scale + bv.w;
        if (RELU) {
            o.x = fmaxf(o.x, 0.f); o.y = fmaxf(o.y, 0.f);
            o.z = fmaxf(o.z, 0.f); o.w = fmaxf(o.w, 0.f);
        }
        *(float4*)(out + (size_t)wid * 64 + l4 * 4) = o;
    }
}

extern "C" void kernel_launch(void* const* d_in, const int* in_sizes, int n_in,
                              void* d_out, int out_size, void* d_ws, size_t ws_size,
                              hipStream_t stream) {
    const float* x  = (const float*)d_in[0];
    const int*   ei = (const int*)d_in[1];
    const float* W1 = (const float*)d_in[2];
    const float* b1 = (const float*)d_in[3];
    const float* W2 = (const float*)d_in[4];
    const float* b2 = (const float*)d_in[5];
    const float* W3 = (const float*)d_in[6];
    const float* b3 = (const float*)d_in[7];
    float* out = (float*)d_out;

    const int n = in_sizes[0] / 128;      // 100000
    const int E = in_sizes[1] / 2;        // 1600000
    const int* srcA = ei;
    const int* dstA = ei + E;

    // ---- workspace carve (aligned to 256B) ----
    auto alignup = [](size_t v) { return (v + 255) & ~(size_t)255; };
    char* base = (char*)d_ws;
    size_t off = 0;
    int* deg    = (int*)(base + off); off = alignup(off + (size_t)n * 4);
    int* fill   = (int*)(base + off); off = alignup(off + (size_t)n * 4);
    int* rowptr = (int*)(base + off); off = alignup(off + (size_t)n * 4);
    int* bsum   = (int*)(base + off); off = alignup(off + (size_t)1024 * 4);
    int* colidx = (int*)(base + off); off = alignup(off + (size_t)E * 4);
    float* dinv = (float*)(base + off); off = alignup(off + (size_t)n * 4);
    float* Hb   = (float*)(base + off); off = alignup(off + (size_t)n * 128 * 4);
    float* Yb   = (float*)(base + off); off = alignup(off + (size_t)n * 128 * 4);
    (void)ws_size;

    const int nbN = (n + BLK - 1) / BLK;      // 391
    const int nbE = (E + BLK - 1) / BLK;

    // ---- prep: degrees, dinv, CSR ----
    init_deg_fill<<<nbN, BLK, 0, stream>>>(deg, fill, n);
    count_deg<<<nbE, BLK, 0, stream>>>(dstA, deg, E);
    compute_dinv<<<nbN, BLK, 0, stream>>>(deg, dinv, n);
    scan_block_sums<<<nbN, BLK, 0, stream>>>(deg, bsum, n);
    scan_partials_excl<<<1, 512, 0, stream>>>(bsum, nbN);
    scan_write_rowptr<<<nbN, BLK, 0, stream>>>(deg, bsum, rowptr, n);
    place_edges<<<nbE, BLK, 0, stream>>>(srcA, dstA, rowptr, fill, colidx, E);

    const int aggBlocks = (n * 64 + BLK - 1) / BLK;   // wave per node

    // ---- layer 1: x @ W1 -> agg -> relu -> Hb ----
    gemm_tiled<128><<<(n + 63) / 64, 256, 0, stream>>>(x, W1, Yb, n);
    agg128<true><<<aggBlocks, BLK, 0, stream>>>(Yb, rowptr, deg, dinv, colidx, b1, Hb, n);

    // ---- layer 2 ----
    gemm_tiled<128><<<(n + 63) / 64, 256, 0, stream>>>(Hb, W2, Yb, n);
    agg128<true><<<aggBlocks, BLK, 0, stream>>>(Yb, rowptr, deg, dinv, colidx, b2, Hb, n);

    // ---- layer 3 (out dim 64, no relu) ----
    gemm_tiled<64><<<(n + 127) / 128, 256, 0, stream>>>(Hb, W3, Yb, n);
    agg64<false><<<aggBlocks, BLK, 0, stream>>>(Yb, rowptr, deg, dinv, colidx, b3, out, n);
}

// Round 4
// 597.356 us; speedup vs baseline: 10.9515x; 1.0253x over previous
//
#include <hip/hip_runtime.h>
#include <math.h>

// ---------------------------------------------------------------------------
// GCN 3-layer forward, fp32.
//  per layer: Ys = dinv .* (H @ W) ;  out_i = dinv_i*( Ys_i + sum_e Ys[src_e] )
//                                             / deg_i + b
// CSR-by-dst built on device each call; segments padded to multiples of 8,
// holes point at zero-row index n (Ys has n+1 rows, row n = 0).
// R2: LDS-tiled register-blocked GEMM (no spills).
// R3: multi-row-in-flight gather (half/quarter lane split).
// R4: shfl-free aggregation — dinv folded into Y rows at GEMM epilogue,
//     edge metadata via uniform int4 broadcast loads, padded CSR (no tails).
// ---------------------------------------------------------------------------

#define BLK 256

__global__ void init_deg_fill(int* __restrict__ deg, int* __restrict__ fill, int n) {
    int i = blockIdx.x * blockDim.x + threadIdx.x;
    if (i < n) { deg[i] = 1; fill[i] = 0; }   // deg starts at 1 (self-loop)
}

__global__ void fill_colpad(int* __restrict__ colidx, int val, int len) {
    int i = blockIdx.x * blockDim.x + threadIdx.x;
    if (i < len) colidx[i] = val;
}

__global__ void count_deg(const int* __restrict__ dst, int* __restrict__ deg, int E) {
    int e = blockIdx.x * blockDim.x + threadIdx.x;
    if (e < E) atomicAdd(&deg[dst[e]], 1);
}

__global__ void compute_dinv(const int* __restrict__ deg, float* __restrict__ dinv, int n) {
    int i = blockIdx.x * blockDim.x + threadIdx.x;
    if (i < n) dinv[i] = 1.0f / sqrtf((float)deg[i]);
}

// padded per-node edge capacity: roundup8(deg-1)
__device__ __forceinline__ int padcap(int d) { return (d - 1 + 7) & ~7; }

// ---- exclusive scan of padcap(deg) into rowptr, 3 passes ----
__global__ void scan_block_sums(const int* __restrict__ deg, int* __restrict__ bsum, int n) {
    __shared__ int s[BLK];
    int i = blockIdx.x * BLK + threadIdx.x;
    s[threadIdx.x] = (i < n) ? padcap(deg[i]) : 0;
    __syncthreads();
    for (int off = BLK / 2; off > 0; off >>= 1) {
        if (threadIdx.x < off) s[threadIdx.x] += s[threadIdx.x + off];
        __syncthreads();
    }
    if (threadIdx.x == 0) bsum[blockIdx.x] = s[0];
}

__global__ void scan_partials_excl(int* __restrict__ bsum, int nb) {
    __shared__ int a[512];
    __shared__ int b[512];
    int t = threadIdx.x;
    int v = (t < nb) ? bsum[t] : 0;
    a[t] = v;
    __syncthreads();
    int* s = a; int* d = b;
    for (int off = 1; off < 512; off <<= 1) {
        int val = s[t];
        if (t >= off) val += s[t - off];
        d[t] = val;
        __syncthreads();
        int* tmp = s; s = d; d = tmp;
    }
    if (t < nb) bsum[t] = s[t] - v;   // exclusive
}

__global__ void scan_write_rowptr(const int* __restrict__ deg, const int* __restrict__ bsum,
                                  int* __restrict__ rowptr, int n) {
    __shared__ int a[BLK];
    __shared__ int b[BLK];
    int t = threadIdx.x;
    int i = blockIdx.x * BLK + t;
    int v = (i < n) ? padcap(deg[i]) : 0;
    a[t] = v;
    __syncthreads();
    int* s = a; int* d = b;
    for (int off = 1; off < BLK; off <<= 1) {
        int val = s[t];
        if (t >= off) val += s[t - off];
        d[t] = val;
        __syncthreads();
        int* tmp = s; s = d; d = tmp;
    }
    if (i < n) rowptr[i] = (s[t] - v) + bsum[blockIdx.x];
}

__global__ void place_edges(const int* __restrict__ src, const int* __restrict__ dst,
                            const int* __restrict__ rowptr, int* __restrict__ fill,
                            int* __restrict__ colidx, int E) {
    int e = blockIdx.x * blockDim.x + threadIdx.x;
    if (e < E) {
        int d = dst[e];
        int pos = rowptr[d] + atomicAdd(&fill[d], 1);
        colidx[pos] = src[e];
    }
}

// ---- GEMM: Ys[n+1,KOUT]; rows<n: dinv[row]*(H@W); row n: zeros ----
template <int KOUT>
__global__ __launch_bounds__(256) void gemm_tiled(const float* __restrict__ H,
                                                  const float* __restrict__ W,
                                                  const float* __restrict__ dinv,
                                                  float* __restrict__ Y, int n) {
    constexpr int ROWS = (KOUT == 128) ? 64 : 128;
    constexpr int HSTR = 36;  // padded k-stride: float4 aligned, conflict-free reads
    __shared__ float Hl[ROWS][HSTR];   // [row][kk]
    __shared__ float Wl[32][KOUT];     // [kk][c]

    const int t = threadIdx.x;
    const int wave = t >> 6, lane = t & 63;
    const int rg = lane >> 3;          // 0..7 row group
    const int cg = lane & 7;           // 0..7 col group
    const int rpanel = (KOUT == 128) ? (wave >> 1) : wave;
    const int cpanel = (KOUT == 128) ? (wave & 1) : 0;
    const int row0 = blockIdx.x * ROWS;
    const int cbase = cpanel * 64 + cg * 8;

    if (blockIdx.x == 0 && t < KOUT) Y[(size_t)n * KOUT + t] = 0.f;  // zero pad-row

    float acc[4][8];
#pragma unroll
    for (int i = 0; i < 4; i++)
#pragma unroll
        for (int j = 0; j < 8; j++) acc[i][j] = 0.f;

    for (int kt = 0; kt < 128; kt += 32) {
        // stage H tile: ROWS x 32 (8 threads/row, float4 each; coalesced 128B/row)
#pragma unroll
        for (int s = 0; s < ROWS / 32; s++) {
            int r = s * 32 + (t >> 3);
            int kk = (t & 7) * 4;
            int row = row0 + r;
            float4 v = make_float4(0.f, 0.f, 0.f, 0.f);
            if (row < n) v = *(const float4*)(H + (size_t)row * 128 + kt + kk);
            Hl[r][kk] = v.x; Hl[r][kk + 1] = v.y; Hl[r][kk + 2] = v.z; Hl[r][kk + 3] = v.w;
        }
        // stage W tile: 32 x KOUT, contiguous chunk
        {
            const float* Wg = W + (size_t)kt * KOUT;
            float* Wf = &Wl[0][0];
            for (int idx = t * 4; idx < 32 * KOUT; idx += 1024) {
                *(float4*)(Wf + idx) = *(const float4*)(Wg + idx);
            }
        }
        __syncthreads();

#pragma unroll 2
        for (int kk = 0; kk < 32; kk += 4) {
            float4 a[4];
#pragma unroll
            for (int i = 0; i < 4; i++)
                a[i] = *(const float4*)(&Hl[rpanel * 32 + rg + 8 * i][kk]);
#pragma unroll
            for (int q = 0; q < 4; q++) {
                float4 w0 = *(const float4*)(&Wl[kk + q][cbase]);
                float4 w1 = *(const float4*)(&Wl[kk + q][cbase + 4]);
#pragma unroll
                for (int i = 0; i < 4; i++) {
                    float av = (q == 0) ? a[i].x : (q == 1) ? a[i].y : (q == 2) ? a[i].z : a[i].w;
                    acc[i][0] += av * w0.x; acc[i][1] += av * w0.y;
                    acc[i][2] += av * w0.z; acc[i][3] += av * w0.w;
                    acc[i][4] += av * w1.x; acc[i][5] += av * w1.y;
                    acc[i][6] += av * w1.z; acc[i][7] += av * w1.w;
                }
            }
        }
        __syncthreads();
    }

#pragma unroll
    for (int i = 0; i < 4; i++) {
        int row = row0 + rpanel * 32 + rg + 8 * i;
        if (row < n) {
            float dv = dinv[row];
            float* yp = Y + (size_t)row * KOUT + cbase;
            *(float4*)yp = make_float4(dv * acc[i][0], dv * acc[i][1], dv * acc[i][2], dv * acc[i][3]);
            *(float4*)(yp + 4) = make_float4(dv * acc[i][4], dv * acc[i][5], dv * acc[i][6], dv * acc[i][7]);
        }
    }
}

// ---- aggregation KOUT=128: wave/node, lane-halves own full rows (float4 x32),
// shfl-free: 8-edge batches via two uniform int4 metadata loads, pipelined. ----
template <bool RELU>
__global__ __launch_bounds__(256) void agg128(const float* __restrict__ Ys,
                                              const int* __restrict__ rowptr,
                                              const int* __restrict__ deg,
                                              const float* __restrict__ dinv,
                                              const int* __restrict__ colidx,
                                              const float* __restrict__ bias,
                                              float* __restrict__ out, int n) {
    int wid = (blockIdx.x * blockDim.x + threadIdx.x) >> 6;
    int lane = threadIdx.x & 63;
    if (wid >= n) return;
    const int half = lane >> 5;
    const int l5 = lane & 31;

    int start = __builtin_amdgcn_readfirstlane(rowptr[wid]);
    int dg    = __builtin_amdgcn_readfirstlane(deg[wid]);
    int mpad  = padcap(dg);
    float di = dinv[wid];

    float4 acc = make_float4(0.f, 0.f, 0.f, 0.f);
    if (half == 0) {   // self term (Ys already includes dinv_i)
        acc = *(const float4*)(Ys + ((size_t)wid << 7) + l5 * 4);
    }

    const int4* cp4 = (const int4*)(colidx + start);   // start % 8 == 0 -> aligned
    int4 a = cp4[0], b = cp4[1];                        // safe: holes/pads valid
    for (int j = 0; j < mpad; j += 8) {
        int4 na = cp4[(j >> 2) + 2];
        int4 nb = cp4[(j >> 2) + 3];
#define ROW2(p, q)                                                              \
        {                                                                       \
            int se = half ? (q) : (p);                                          \
            float4 yv = *(const float4*)(Ys + ((size_t)se << 7) + l5 * 4);      \
            acc.x += yv.x; acc.y += yv.y; acc.z += yv.z; acc.w += yv.w;         \
        }
        ROW2(a.x, a.y) ROW2(a.z, a.w) ROW2(b.x, b.y) ROW2(b.z, b.w)
#undef ROW2
        a = na; b = nb;
    }
    // combine halves
    acc.x += __shfl_xor(acc.x, 32);
    acc.y += __shfl_xor(acc.y, 32);
    acc.z += __shfl_xor(acc.z, 32);
    acc.w += __shfl_xor(acc.w, 32);

    if (half == 0) {
        float scale = di / (float)dg;
        float4 bv = *(const float4*)(bias + l5 * 4);
        float4 o;
        o.x = acc.x * scale + bv.x;
        o.y = acc.y * scale + bv.y;
        o.z = acc.z * scale + bv.z;
        o.w = acc.w * scale + bv.w;
        if (RELU) {
            o.x = fmaxf(o.x, 0.f); o.y = fmaxf(o.y, 0.f);
            o.z = fmaxf(o.z, 0.f); o.w = fmaxf(o.w, 0.f);
        }
        *(float4*)(out + ((size_t)wid << 7) + l5 * 4) = o;
    }
}

// ---- aggregation KOUT=64: lane-quarters own rows (float4 x16), shfl-free ----
template <bool RELU>
__global__ __launch_bounds__(256) void agg64(const float* __restrict__ Ys,
                                             const int* __restrict__ rowptr,
                                             const int* __restrict__ deg,
                                             const float* __restrict__ dinv,
                                             const int* __restrict__ colidx,
                                             const float* __restrict__ bias,
                                             float* __restrict__ out, int n) {
    int wid = (blockIdx.x * blockDim.x + threadIdx.x) >> 6;
    int lane = threadIdx.x & 63;
    if (wid >= n) return;
    const int q = lane >> 4;
    const int l4 = lane & 15;

    int start = __builtin_amdgcn_readfirstlane(rowptr[wid]);
    int dg    = __builtin_amdgcn_readfirstlane(deg[wid]);
    int mpad  = padcap(dg);
    float di = dinv[wid];

    float4 acc = make_float4(0.f, 0.f, 0.f, 0.f);
    if (q == 0) {
        acc = *(const float4*)(Ys + ((size_t)wid << 6) + l4 * 4);
    }

    const int4* cp4 = (const int4*)(colidx + start);
    int4 a = cp4[0], b = cp4[1];
    for (int j = 0; j < mpad; j += 8) {
        int4 na = cp4[(j >> 2) + 2];
        int4 nb = cp4[(j >> 2) + 3];
#define ROW4(p0, p1, p2, p3)                                                    \
        {                                                                       \
            int se = (q == 0) ? (p0) : (q == 1) ? (p1) : (q == 2) ? (p2) : (p3);\
            float4 yv = *(const float4*)(Ys + ((size_t)se << 6) + l4 * 4);      \
            acc.x += yv.x; acc.y += yv.y; acc.z += yv.z; acc.w += yv.w;         \
        }
        ROW4(a.x, a.y, a.z, a.w) ROW4(b.x, b.y, b.z, b.w)
#undef ROW4
        a = na; b = nb;
    }
    // combine quarters
    acc.x += __shfl_xor(acc.x, 16); acc.x += __shfl_xor(acc.x, 32);
    acc.y += __shfl_xor(acc.y, 16); acc.y += __shfl_xor(acc.y, 32);
    acc.z += __shfl_xor(acc.z, 16); acc.z += __shfl_xor(acc.z, 32);
    acc.w += __shfl_xor(acc.w, 16); acc.w += __shfl_xor(acc.w, 32);

    if (q == 0) {
        float scale = di / (float)dg;
        float4 bv = *(const float4*)(bias + l4 * 4);
        float4 o;
        o.x = acc.x * scale + bv.x;
        o.y = acc.y * scale + bv.y;
        o.z = acc.z * scale + bv.z;
        o.w = acc.w * scale + bv.w;
        if (RELU) {
            o.x = fmaxf(o.x, 0.f); o.y = fmaxf(o.y, 0.f);
            o.z = fmaxf(o.z, 0.f); o.w = fmaxf(o.w, 0.f);
        }
        *(float4*)(out + ((size_t)wid << 6) + l4 * 4) = o;
    }
}

extern "C" void kernel_launch(void* const* d_in, const int* in_sizes, int n_in,
                              void* d_out, int out_size, void* d_ws, size_t ws_size,
                              hipStream_t stream) {
    const float* x  = (const float*)d_in[0];
    const int*   ei = (const int*)d_in[1];
    const float* W1 = (const float*)d_in[2];
    const float* b1 = (const float*)d_in[3];
    const float* W2 = (const float*)d_in[4];
    const float* b2 = (const float*)d_in[5];
    const float* W3 = (const float*)d_in[6];
    const float* b3 = (const float*)d_in[7];
    float* out = (float*)d_out;

    const int n = in_sizes[0] / 128;      // 100000
    const int E = in_sizes[1] / 2;        // 1600000
    const int* srcA = ei;
    const int* dstA = ei + E;
    const int Epad = E + 8 * n + 16;      // CSR padded to 8 per node + slack

    // ---- workspace carve (aligned to 256B) ----
    auto alignup = [](size_t v) { return (v + 255) & ~(size_t)255; };
    char* base = (char*)d_ws;
    size_t off = 0;
    int* deg    = (int*)(base + off); off = alignup(off + (size_t)n * 4);
    int* fill   = (int*)(base + off); off = alignup(off + (size_t)n * 4);
    int* rowptr = (int*)(base + off); off = alignup(off + (size_t)n * 4);
    int* bsum   = (int*)(base + off); off = alignup(off + (size_t)1024 * 4);
    int* colidx = (int*)(base + off); off = alignup(off + (size_t)Epad * 4);
    float* dinv = (float*)(base + off); off = alignup(off + (size_t)n * 4);
    float* Hb   = (float*)(base + off); off = alignup(off + (size_t)n * 128 * 4);
    float* Yb   = (float*)(base + off); off = alignup(off + (size_t)(n + 1) * 128 * 4);
    (void)ws_size;

    const int nbN = (n + BLK - 1) / BLK;      // 391
    const int nbE = (E + BLK - 1) / BLK;
    const int nbP = (Epad + BLK - 1) / BLK;

    // ---- prep: degrees, dinv, padded CSR (holes -> zero-row index n) ----
    init_deg_fill<<<nbN, BLK, 0, stream>>>(deg, fill, n);
    fill_colpad<<<nbP, BLK, 0, stream>>>(colidx, n, Epad);
    count_deg<<<nbE, BLK, 0, stream>>>(dstA, deg, E);
    compute_dinv<<<nbN, BLK, 0, stream>>>(deg, dinv, n);
    scan_block_sums<<<nbN, BLK, 0, stream>>>(deg, bsum, n);
    scan_partials_excl<<<1, 512, 0, stream>>>(bsum, nbN);
    scan_write_rowptr<<<nbN, BLK, 0, stream>>>(deg, bsum, rowptr, n);
    place_edges<<<nbE, BLK, 0, stream>>>(srcA, dstA, rowptr, fill, colidx, E);

    const int aggBlocks = (n * 64 + BLK - 1) / BLK;   // wave per node

    // ---- layer 1: x @ W1 -> agg -> relu -> Hb ----
    gemm_tiled<128><<<(n + 63) / 64, 256, 0, stream>>>(x, W1, dinv, Yb, n);
    agg128<true><<<aggBlocks, BLK, 0, stream>>>(Yb, rowptr, deg, dinv, colidx, b1, Hb, n);

    // ---- layer 2 ----
    gemm_tiled<128><<<(n + 63) / 64, 256, 0, stream>>>(Hb, W2, dinv, Yb, n);
    agg128<true><<<aggBlocks, BLK, 0, stream>>>(Yb, rowptr, deg, dinv, colidx, b2, Hb, n);

    // ---- layer 3 (out dim 64, no relu) ----
    gemm_tiled<64><<<(n + 127) / 128, 256, 0, stream>>>(Hb, W3, dinv, Yb, n);
    agg64<false><<<aggBlocks, BLK, 0, stream>>>(Yb, rowptr, deg, dinv, colidx, b3, out, n);
}